// Round 10
// baseline (314.306 us; speedup 1.0000x reference)
//
#include <hip/hip_runtime.h>

// Problem constants
#define T     4
#define WQ    75
#define C     640
#define HW    100
#define WAY   5
#define SHOT  5
#define NT    5
#define NPAIR 15

// q tiles: [tq][tile(5)][oct(14)][row(128)][8] bf16; octet 12 half-zero, 13 zero
#define QOCT  14
#define QTS   (QOCT*128*8)        // 14336 shorts = 28 KB
// s tiles (tight k-pack): [tw][tile(5)][oct(64)][row(128)][8]; k = sh*100+n, 500 real + 12 zero
#define SOCT  64
#define STS   (SOCT*128*8)        // 65536 shorts = 128 KB

// ws layout (bytes)
#define WS_COVB_OFF  0            // 20*15*16384*2 = 9,830,400 (bf16, fragment order)
#define WS_QTB_OFF   9830400      // 300*5*14336*2 = 43,008,000
#define WS_QTBW_OFF  52838400     // 300*5*14336*2 = 43,008,000
#define WS_STB_OFF   95846400     // 20*5*65536*2  = 13,107,200

typedef __attribute__((ext_vector_type(8)))  short bfrag8;
typedef __attribute__((ext_vector_type(16))) float f32x16;

__device__ __forceinline__ unsigned short f2bf(float x) {
    unsigned int u = __float_as_uint(x);
    return (unsigned short)((u + 0x7fffu + ((u >> 16) & 1u)) >> 16);   // RNE
}
__device__ __forceinline__ float bflo(unsigned u) { return __uint_as_float(u << 16); }
__device__ __forceinline__ float bfhi(unsigned u) { return __uint_as_float(u & 0xffff0000u); }

__device__ __forceinline__ void pair_ij(int p, int& ti, int& tj) {
    int base = 0;
    #pragma unroll
    for (int a = 0; a < NT; ++a) {
        int cnt = NT - a;
        if (p < base + cnt) { ti = a; tj = a + (p - base); return; }
        base += cnt;
    }
    ti = 0; tj = 0;
}

// ---------- prep: out-init + qpack(+weighted) + spack(tight k) ----------
// grid: [0,3000) qpack (cb=bid%10, tq=bid/10); [3000,3400) spack (rb=idx%20, tw=idx/20); 3400 init.
__global__ __launch_bounds__(256)
void prep_kernel(const float* __restrict__ qf, const float* __restrict__ sf,
                 const float* __restrict__ convw, const float* __restrict__ bias,
                 unsigned short* __restrict__ qtb, unsigned short* __restrict__ qtbw,
                 unsigned short* __restrict__ stb, float* __restrict__ out) {
    int bid = blockIdx.x, tid = threadIdx.x;

    if (bid < 3000) {
        __shared__ float ld[64 * 101];
        __shared__ float wl[HW];
        __shared__ float mpart[64][4];
        __shared__ float mean[64];
        int cb = bid % 10, tq = bid / 10;
        if (tid < HW) wl[tid] = convw[tid];
        const float* src = qf + ((size_t)tq * C + cb * 64) * HW;
        #pragma unroll
        for (int it = 0; it < 7; ++it) {
            int idx = tid + it * 256;
            if (idx < 1600) {
                float4 v = ((const float4*)src)[idx];
                int f = idx * 4;
                float vs[4] = {v.x, v.y, v.z, v.w};
                #pragma unroll
                for (int j = 0; j < 4; ++j) {
                    int ff = f + j;
                    ld[(ff / HW) * 101 + (ff % HW)] = vs[j];
                }
            }
        }
        __syncthreads();
        {
            int row = tid & 63, part = tid >> 6;
            float ps = 0.f;
            #pragma unroll
            for (int i = 0; i < 25; ++i) ps += ld[row * 101 + part * 25 + i];
            mpart[row][part] = ps;
        }
        __syncthreads();
        if (tid < 64) mean[tid] = (mpart[tid][0] + mpart[tid][1] + mpart[tid][2] + mpart[tid][3]) * (1.0f / HW);
        __syncthreads();
        int tile = cb >> 1, trowbase = (cb & 1) << 6;
        #pragma unroll
        for (int it = 0; it < 4; ++it) {
            int task = tid + it * 256;              // 896 tasks: row(64) x oct(14)
            if (task < 64 * QOCT) {
                int row = task & 63, oct = task >> 6;
                float m = mean[row];
                unsigned short ob[8] __attribute__((aligned(16)));
                unsigned short ow[8] __attribute__((aligned(16)));
                #pragma unroll
                for (int j = 0; j < 8; ++j) {
                    int n = oct * 8 + j;
                    float v = (n < HW) ? (ld[row * 101 + n] - m) : 0.f;
                    float w = (n < HW) ? wl[n] : 0.f;
                    ob[j] = f2bf(v); ow[j] = f2bf(v * w);
                }
                size_t dst = ((((size_t)tq * NT + tile) * QOCT + oct) * 128 + trowbase + row) * 8;
                *(uint4*)(qtb + dst)  = *(uint4*)ob;
                *(uint4*)(qtbw + dst) = *(uint4*)ow;
            }
        }
    } else if (bid < 3400) {
        // spack: 32 c-rows, all 5 shots resident -> tight k write
        __shared__ float ld2[32 * 504];             // [row][k], k = sh*100+n
        __shared__ float mpart2[32][8];
        __shared__ float mean2[32];
        int idx2 = bid - 3000;
        int rb = idx2 % 20, tw = idx2 / 20;
        int r0 = rb * 32;
        for (int sh = 0; sh < SHOT; ++sh) {
            const float* src = sf + ((size_t)(tw * SHOT + sh) * C + r0) * HW;
            #pragma unroll
            for (int it = 0; it < 4; ++it) {
                int idx = tid + it * 256;
                if (idx < 800) {
                    float4 v = ((const float4*)src)[idx];
                    int f = idx * 4;
                    int row = f / HW, n = f % HW;   // float4 never crosses a row (100%4==0)
                    *(float4*)&ld2[row * 504 + sh * HW + n] = v;
                }
            }
        }
        __syncthreads();
        {
            int row = tid & 31, part = tid >> 5;    // 8 parts x 64 els
            float ps = 0.f;
            #pragma unroll
            for (int i = 0; i < 64; ++i) {
                int k = part * 64 + i;
                if (k < 500) ps += ld2[row * 504 + k];
            }
            mpart2[row][part] = ps;
        }
        __syncthreads();
        if (tid < 32) {
            float s = 0.f;
            #pragma unroll
            for (int p2 = 0; p2 < 8; ++p2) s += mpart2[tid][p2];
            mean2[tid] = s * (1.0f / (SHOT * HW));
        }
        __syncthreads();
        #pragma unroll
        for (int it = 0; it < 8; ++it) {
            int task = tid + it * 256;              // 2048 tasks: oct(64) x row(32)
            int row = task & 31, oct = task >> 5;
            float m = mean2[row];
            unsigned short ob[8] __attribute__((aligned(16)));
            #pragma unroll
            for (int j = 0; j < 8; ++j) {
                int k = oct * 8 + j;
                ob[j] = (k < 500) ? f2bf(ld2[row * 504 + k] - m) : (unsigned short)0;
            }
            int crow = r0 + row;
            int tile = crow >> 7, trow = crow & 127;
            size_t dst = ((((size_t)tw * NT + tile) * SOCT + oct) * 128 + trow) * 8;
            *(uint4*)(stb + dst) = *(uint4*)ob;
        }
    } else {
        float b = bias[0];
        for (int i = tid; i < T * WQ * WAY; i += 256) out[i] = b;
    }
}

// ---------- cov: direct global->VGPR fragment loads, tight k (32 s-iters) ----------
// grid = (NPAIR, T*WAY)
__global__ __launch_bounds__(256, 4)
void cov_kernel(const unsigned short* __restrict__ stb, unsigned short* __restrict__ covb) {
    int p = blockIdx.x, tw = blockIdx.y;
    int ti, tj; pair_ij(p, ti, tj);
    int tid = threadIdx.x, lane = tid & 63, wave = tid >> 6;
    int qm = wave & 1, qn = wave >> 1, lh = lane >> 5, ls = lane & 31;
    int rA = qm * 64 + ls, rB = qn * 64 + ls;
    const unsigned short* Ab = stb + ((size_t)tw * NT + ti) * STS;
    const unsigned short* Bb = stb + ((size_t)tw * NT + tj) * STS;

    f32x16 acc[4];
    #pragma unroll
    for (int b = 0; b < 4; ++b)
        #pragma unroll
        for (int e = 0; e < 16; ++e) acc[b][e] = 0.f;

    #pragma unroll 4
    for (int s = 0; s < 32; ++s) {
        int oc = s * 2 + lh;
        const unsigned short* ap = Ab + (size_t)oc * 1024;
        const unsigned short* bp = Bb + (size_t)oc * 1024;
        bfrag8 a0 = *(const bfrag8*)&ap[rA * 8];
        bfrag8 a1 = *(const bfrag8*)&ap[(rA + 32) * 8];
        bfrag8 b0 = *(const bfrag8*)&bp[rB * 8];
        bfrag8 b1 = *(const bfrag8*)&bp[(rB + 32) * 8];
        acc[0] = __builtin_amdgcn_mfma_f32_32x32x16_bf16(a0, b0, acc[0], 0, 0, 0);
        acc[1] = __builtin_amdgcn_mfma_f32_32x32x16_bf16(a0, b1, acc[1], 0, 0, 0);
        acc[2] = __builtin_amdgcn_mfma_f32_32x32x16_bf16(a1, b0, acc[2], 0, 0, 0);
        acc[3] = __builtin_amdgcn_mfma_f32_32x32x16_bf16(a1, b1, acc[3], 0, 0, 0);
    }

    const float inv = 1.0f / (HW - 1);
    unsigned short* cb = covb + ((size_t)tw * NPAIR + p) * 16384;
    #pragma unroll
    for (int b = 0; b < 4; ++b) {
        unsigned ow[8];
        #pragma unroll
        for (int wd = 0; wd < 8; ++wd)
            ow[wd] = (unsigned)f2bf(acc[b][2 * wd] * inv)
                   | ((unsigned)f2bf(acc[b][2 * wd + 1] * inv) << 16);
        size_t off = (size_t)((wave * 4 + b) * 64 + lane) * 16;
        *(uint4*)(cb + off)     = *(uint4*)&ow[0];
        *(uint4*)(cb + off + 8) = *(uint4*)&ow[4];
    }
}

// ---------- score: one query per block -> grid (p=15, q=75, t=4) = 4500 blocks ----------
__global__ __launch_bounds__(256, 4)
void score_kernel(const unsigned short* __restrict__ qtb, const unsigned short* __restrict__ qtbw,
                  const unsigned short* __restrict__ covb, float* __restrict__ out) {
    __shared__ float red[4][WAY];
    int p = blockIdx.x, q = blockIdx.y, t = blockIdx.z;
    int ti, tj; pair_ij(p, ti, tj);
    int tid = threadIdx.x, lane = tid & 63, wave = tid >> 6;
    int qm = wave & 1, qn = wave >> 1, lh = lane >> 5, ls = lane & 31;
    int rA = qm * 64 + ls, rB = qn * 64 + ls;
    float mult = (ti == tj) ? 1.0f : 2.0f;
    const unsigned short* cbase = covb + ((size_t)(t * WAY) * NPAIR + p) * 16384;

    const unsigned short* Ab = qtbw + ((size_t)(t * WQ + q) * NT + ti) * QTS;
    const unsigned short* Bb = qtb  + ((size_t)(t * WQ + q) * NT + tj) * QTS;

    f32x16 acc[4];
    #pragma unroll
    for (int b = 0; b < 4; ++b)
        #pragma unroll
        for (int e = 0; e < 16; ++e) acc[b][e] = 0.f;

    #pragma unroll
    for (int s = 0; s < 7; ++s) {
        int oc = s * 2 + lh;
        const unsigned short* ap = Ab + (size_t)oc * 1024;
        const unsigned short* bp = Bb + (size_t)oc * 1024;
        bfrag8 a0 = *(const bfrag8*)&ap[rA * 8];
        bfrag8 a1 = *(const bfrag8*)&ap[(rA + 32) * 8];
        bfrag8 b0 = *(const bfrag8*)&bp[rB * 8];
        bfrag8 b1 = *(const bfrag8*)&bp[(rB + 32) * 8];
        acc[0] = __builtin_amdgcn_mfma_f32_32x32x16_bf16(a0, b0, acc[0], 0, 0, 0);
        acc[1] = __builtin_amdgcn_mfma_f32_32x32x16_bf16(a0, b1, acc[1], 0, 0, 0);
        acc[2] = __builtin_amdgcn_mfma_f32_32x32x16_bf16(a1, b0, acc[2], 0, 0, 0);
        acc[3] = __builtin_amdgcn_mfma_f32_32x32x16_bf16(a1, b1, acc[3], 0, 0, 0);
    }

    // per-way Frobenius dot + immediate reduce
    #pragma unroll 1
    for (int w = 0; w < WAY; ++w) {
        const unsigned short* cb = cbase + (size_t)w * NPAIR * 16384;
        float s = 0.f;
        #pragma unroll
        for (int b = 0; b < 4; ++b) {
            size_t off = (size_t)((wave * 4 + b) * 64 + lane) * 16;
            uint4 u0 = *(const uint4*)(cb + off);
            uint4 u1 = *(const uint4*)(cb + off + 8);
            unsigned uw[8] = {u0.x, u0.y, u0.z, u0.w, u1.x, u1.y, u1.z, u1.w};
            #pragma unroll
            for (int wd = 0; wd < 8; ++wd)
                s += bflo(uw[wd]) * acc[b][2 * wd] + bfhi(uw[wd]) * acc[b][2 * wd + 1];
        }
        float v = s * mult;
        #pragma unroll
        for (int off2 = 32; off2 > 0; off2 >>= 1) v += __shfl_down(v, off2);
        if (lane == 0) red[wave][w] = v;
    }
    __syncthreads();
    if (tid < WAY) {
        float tot = red[0][tid] + red[1][tid] + red[2][tid] + red[3][tid];
        atomicAdd(&out[(size_t)(t * WQ + q) * WAY + tid], tot);
    }
}

extern "C" void kernel_launch(void* const* d_in, const int* in_sizes, int n_in,
                              void* d_out, int out_size, void* d_ws, size_t ws_size,
                              hipStream_t stream) {
    const float* qf = (const float*)d_in[0];   // (4,75,640,10,10)
    const float* sf = (const float*)d_in[1];   // (4,25,640,10,10)
    const float* cw = (const float*)d_in[2];   // (1,1,100)
    const float* cb = (const float*)d_in[3];   // (1,)
    float* out = (float*)d_out;                // (4,75,5)

    unsigned short* covb = (unsigned short*)((char*)d_ws + WS_COVB_OFF);
    unsigned short* qtb  = (unsigned short*)((char*)d_ws + WS_QTB_OFF);
    unsigned short* qtbw = (unsigned short*)((char*)d_ws + WS_QTBW_OFF);
    unsigned short* stb  = (unsigned short*)((char*)d_ws + WS_STB_OFF);

    prep_kernel<<<3401, 256, 0, stream>>>(qf, sf, cw, cb, qtb, qtbw, stb, out);
    cov_kernel<<<dim3(NPAIR, T * WAY), 256, 0, stream>>>(stb, covb);
    score_kernel<<<dim3(NPAIR, WQ, T), 256, 0, stream>>>(qtb, qtbw, covb, out);
}

// Round 11
// 262.071 us; speedup vs baseline: 1.1993x; 1.1993x over previous
//
#include <hip/hip_runtime.h>

// Problem constants
#define T     4
#define WQ    75
#define C     640
#define HW    100
#define WAY   5
#define SHOT  5
#define NT    5
#define NPAIR 15

// q tiles: [tq][tile(5)][oct(14)][row(128)][8] bf16; octet 12 half-zero, 13 zero
#define QOCT  14
#define QTS   (QOCT*128*8)        // 14336 shorts = 28 KB
// s tiles (tight k-pack): [tw][tile(5)][oct(64)][row(128)][8]; k = sh*100+n, 500 real + 12 zero
#define SOCT  64
#define STS   (SOCT*128*8)        // 65536 shorts = 128 KB

// ws layout (bytes)
#define WS_COVB_OFF  0            // 20*15*16384*2 = 9,830,400 (bf16, fragment order)
#define WS_QTB_OFF   9830400      // 300*5*14336*2 = 43,008,000
#define WS_QTBW_OFF  52838400     // 300*5*14336*2 = 43,008,000
#define WS_STB_OFF   95846400     // 20*5*65536*2  = 13,107,200

typedef __attribute__((ext_vector_type(8)))  short bfrag8;
typedef __attribute__((ext_vector_type(16))) float f32x16;

__device__ __forceinline__ unsigned short f2bf(float x) {
    unsigned int u = __float_as_uint(x);
    return (unsigned short)((u + 0x7fffu + ((u >> 16) & 1u)) >> 16);   // RNE
}
__device__ __forceinline__ float bflo(unsigned u) { return __uint_as_float(u << 16); }
__device__ __forceinline__ float bfhi(unsigned u) { return __uint_as_float(u & 0xffff0000u); }

__device__ __forceinline__ void pair_ij(int p, int& ti, int& tj) {
    int base = 0;
    #pragma unroll
    for (int a = 0; a < NT; ++a) {
        int cnt = NT - a;
        if (p < base + cnt) { ti = a; tj = a + (p - base); return; }
        base += cnt;
    }
    ti = 0; tj = 0;
}

__global__ void init_out_kernel(float* __restrict__ out, const float* __restrict__ bias) {
    float b = bias[0];
    for (int i = threadIdx.x; i < T * WQ * WAY; i += 256) out[i] = b;
}

// ---------- qpack: 64 rows/block, grid (10, 300). LDS ~27.5 KB ----------
__global__ __launch_bounds__(256, 4)
void qpack_kernel(const float* __restrict__ qf, const float* __restrict__ convw,
                  unsigned short* __restrict__ qtb, unsigned short* __restrict__ qtbw) {
    __shared__ float ld[64 * 101];
    __shared__ float wl[HW];
    __shared__ float mpart[64][4];
    __shared__ float mean[64];
    int cb = blockIdx.x, tq = blockIdx.y;
    int tid = threadIdx.x;
    if (tid < HW) wl[tid] = convw[tid];
    const float* src = qf + ((size_t)tq * C + cb * 64) * HW;
    #pragma unroll
    for (int it = 0; it < 7; ++it) {
        int idx = tid + it * 256;
        if (idx < 1600) {
            float4 v = ((const float4*)src)[idx];
            int f = idx * 4;
            float vs[4] = {v.x, v.y, v.z, v.w};
            #pragma unroll
            for (int j = 0; j < 4; ++j) {
                int ff = f + j;
                ld[(ff / HW) * 101 + (ff % HW)] = vs[j];
            }
        }
    }
    __syncthreads();
    {
        int row = tid & 63, part = tid >> 6;
        float ps = 0.f;
        #pragma unroll
        for (int i = 0; i < 25; ++i) ps += ld[row * 101 + part * 25 + i];
        mpart[row][part] = ps;
    }
    __syncthreads();
    if (tid < 64) mean[tid] = (mpart[tid][0] + mpart[tid][1] + mpart[tid][2] + mpart[tid][3]) * (1.0f / HW);
    __syncthreads();
    int tile = cb >> 1, trowbase = (cb & 1) << 6;
    #pragma unroll
    for (int it = 0; it < 4; ++it) {
        int task = tid + it * 256;              // 896 tasks: row(64) x oct(14)
        if (task < 64 * QOCT) {
            int row = task & 63, oct = task >> 6;
            float m = mean[row];
            unsigned short ob[8] __attribute__((aligned(16)));
            unsigned short ow[8] __attribute__((aligned(16)));
            #pragma unroll
            for (int j = 0; j < 8; ++j) {
                int n = oct * 8 + j;
                float v = (n < HW) ? (ld[row * 101 + n] - m) : 0.f;
                float w = (n < HW) ? wl[n] : 0.f;
                ob[j] = f2bf(v); ow[j] = f2bf(v * w);
            }
            size_t dst = ((((size_t)tq * NT + tile) * QOCT + oct) * 128 + trowbase + row) * 8;
            *(uint4*)(qtb + dst)  = *(uint4*)ob;
            *(uint4*)(qtbw + dst) = *(uint4*)ow;
        }
    }
}

// ---------- spack: 16 rows/block, tight-k, stride 505 (conflict-free). grid (40, 20) ----------
#define LD2S 505
__global__ __launch_bounds__(256, 4)
void spack_kernel(const float* __restrict__ sf, unsigned short* __restrict__ stb) {
    __shared__ float ld2[16 * LD2S];            // [row][k], k = sh*100+n
    __shared__ float mpart2[16][16];
    __shared__ float mean2[16];
    int rb = blockIdx.x, tw = blockIdx.y;
    int tid = threadIdx.x;
    int r0 = rb * 16;
    for (int sh = 0; sh < SHOT; ++sh) {
        const float* src = sf + ((size_t)(tw * SHOT + sh) * C + r0) * HW;
        #pragma unroll
        for (int it = 0; it < 2; ++it) {
            int idx = tid + it * 256;
            if (idx < 400) {                     // 16 rows x 25 float4
                float4 v = ((const float4*)src)[idx];
                int f = idx * 4;
                int row = f / HW, n = f % HW;    // float4 never crosses a row
                float* d = &ld2[row * LD2S + sh * HW + n];
                d[0] = v.x; d[1] = v.y; d[2] = v.z; d[3] = v.w;
            }
        }
    }
    __syncthreads();
    {
        int row = tid & 15, part = tid >> 4;    // 16 parts x 32 els
        float ps = 0.f;
        #pragma unroll
        for (int i = 0; i < 32; ++i) {
            int k = part * 32 + i;
            if (k < 500) ps += ld2[row * LD2S + k];
        }
        mpart2[row][part] = ps;
    }
    __syncthreads();
    if (tid < 16) {
        float s = 0.f;
        #pragma unroll
        for (int p2 = 0; p2 < 16; ++p2) s += mpart2[tid][p2];
        mean2[tid] = s * (1.0f / (SHOT * HW));
    }
    __syncthreads();
    #pragma unroll
    for (int it = 0; it < 4; ++it) {
        int task = tid + it * 256;              // 1024 tasks: oct(64) x row(16)
        int row = task & 15, oct = task >> 4;
        float m = mean2[row];
        unsigned short ob[8] __attribute__((aligned(16)));
        #pragma unroll
        for (int j = 0; j < 8; ++j) {
            int k = oct * 8 + j;
            ob[j] = (k < 500) ? f2bf(ld2[row * LD2S + k] - m) : (unsigned short)0;
        }
        int crow = r0 + row;
        int tile = crow >> 7, trow = crow & 127;
        size_t dst = ((((size_t)tw * NT + tile) * SOCT + oct) * 128 + trow) * 8;
        *(uint4*)(stb + dst) = *(uint4*)ob;
    }
}

// ---------- cov: direct global->VGPR fragment loads, tight k (32 s-iters) ----------
// grid = (NPAIR, T*WAY)
__global__ __launch_bounds__(256, 4)
void cov_kernel(const unsigned short* __restrict__ stb, unsigned short* __restrict__ covb) {
    int p = blockIdx.x, tw = blockIdx.y;
    int ti, tj; pair_ij(p, ti, tj);
    int tid = threadIdx.x, lane = tid & 63, wave = tid >> 6;
    int qm = wave & 1, qn = wave >> 1, lh = lane >> 5, ls = lane & 31;
    int rA = qm * 64 + ls, rB = qn * 64 + ls;
    const unsigned short* Ab = stb + ((size_t)tw * NT + ti) * STS;
    const unsigned short* Bb = stb + ((size_t)tw * NT + tj) * STS;

    f32x16 acc[4];
    #pragma unroll
    for (int b = 0; b < 4; ++b)
        #pragma unroll
        for (int e = 0; e < 16; ++e) acc[b][e] = 0.f;

    #pragma unroll 4
    for (int s = 0; s < 32; ++s) {
        int oc = s * 2 + lh;
        const unsigned short* ap = Ab + (size_t)oc * 1024;
        const unsigned short* bp = Bb + (size_t)oc * 1024;
        bfrag8 a0 = *(const bfrag8*)&ap[rA * 8];
        bfrag8 a1 = *(const bfrag8*)&ap[(rA + 32) * 8];
        bfrag8 b0 = *(const bfrag8*)&bp[rB * 8];
        bfrag8 b1 = *(const bfrag8*)&bp[(rB + 32) * 8];
        acc[0] = __builtin_amdgcn_mfma_f32_32x32x16_bf16(a0, b0, acc[0], 0, 0, 0);
        acc[1] = __builtin_amdgcn_mfma_f32_32x32x16_bf16(a0, b1, acc[1], 0, 0, 0);
        acc[2] = __builtin_amdgcn_mfma_f32_32x32x16_bf16(a1, b0, acc[2], 0, 0, 0);
        acc[3] = __builtin_amdgcn_mfma_f32_32x32x16_bf16(a1, b1, acc[3], 0, 0, 0);
    }

    const float inv = 1.0f / (HW - 1);
    unsigned short* cb = covb + ((size_t)tw * NPAIR + p) * 16384;
    #pragma unroll
    for (int b = 0; b < 4; ++b) {
        unsigned ow[8];
        #pragma unroll
        for (int wd = 0; wd < 8; ++wd)
            ow[wd] = (unsigned)f2bf(acc[b][2 * wd] * inv)
                   | ((unsigned)f2bf(acc[b][2 * wd + 1] * inv) << 16);
        size_t off = (size_t)((wave * 4 + b) * 64 + lane) * 16;
        *(uint4*)(cb + off)     = *(uint4*)&ow[0];
        *(uint4*)(cb + off + 8) = *(uint4*)&ow[4];
    }
}

// ---------- score: one query per block -> grid (p=15, q=75, t=4) = 4500 blocks ----------
__global__ __launch_bounds__(256, 4)
void score_kernel(const unsigned short* __restrict__ qtb, const unsigned short* __restrict__ qtbw,
                  const unsigned short* __restrict__ covb, float* __restrict__ out) {
    __shared__ float red[4][WAY];
    int p = blockIdx.x, q = blockIdx.y, t = blockIdx.z;
    int ti, tj; pair_ij(p, ti, tj);
    int tid = threadIdx.x, lane = tid & 63, wave = tid >> 6;
    int qm = wave & 1, qn = wave >> 1, lh = lane >> 5, ls = lane & 31;
    int rA = qm * 64 + ls, rB = qn * 64 + ls;
    float mult = (ti == tj) ? 1.0f : 2.0f;
    const unsigned short* cbase = covb + ((size_t)(t * WAY) * NPAIR + p) * 16384;

    const unsigned short* Ab = qtbw + ((size_t)(t * WQ + q) * NT + ti) * QTS;
    const unsigned short* Bb = qtb  + ((size_t)(t * WQ + q) * NT + tj) * QTS;

    f32x16 acc[4];
    #pragma unroll
    for (int b = 0; b < 4; ++b)
        #pragma unroll
        for (int e = 0; e < 16; ++e) acc[b][e] = 0.f;

    #pragma unroll
    for (int s = 0; s < 7; ++s) {
        int oc = s * 2 + lh;
        const unsigned short* ap = Ab + (size_t)oc * 1024;
        const unsigned short* bp = Bb + (size_t)oc * 1024;
        bfrag8 a0 = *(const bfrag8*)&ap[rA * 8];
        bfrag8 a1 = *(const bfrag8*)&ap[(rA + 32) * 8];
        bfrag8 b0 = *(const bfrag8*)&bp[rB * 8];
        bfrag8 b1 = *(const bfrag8*)&bp[(rB + 32) * 8];
        acc[0] = __builtin_amdgcn_mfma_f32_32x32x16_bf16(a0, b0, acc[0], 0, 0, 0);
        acc[1] = __builtin_amdgcn_mfma_f32_32x32x16_bf16(a0, b1, acc[1], 0, 0, 0);
        acc[2] = __builtin_amdgcn_mfma_f32_32x32x16_bf16(a1, b0, acc[2], 0, 0, 0);
        acc[3] = __builtin_amdgcn_mfma_f32_32x32x16_bf16(a1, b1, acc[3], 0, 0, 0);
    }

    // per-way Frobenius dot + immediate reduce
    #pragma unroll 1
    for (int w = 0; w < WAY; ++w) {
        const unsigned short* cb = cbase + (size_t)w * NPAIR * 16384;
        float s = 0.f;
        #pragma unroll
        for (int b = 0; b < 4; ++b) {
            size_t off = (size_t)((wave * 4 + b) * 64 + lane) * 16;
            uint4 u0 = *(const uint4*)(cb + off);
            uint4 u1 = *(const uint4*)(cb + off + 8);
            unsigned uw[8] = {u0.x, u0.y, u0.z, u0.w, u1.x, u1.y, u1.z, u1.w};
            #pragma unroll
            for (int wd = 0; wd < 8; ++wd)
                s += bflo(uw[wd]) * acc[b][2 * wd] + bfhi(uw[wd]) * acc[b][2 * wd + 1];
        }
        float v = s * mult;
        #pragma unroll
        for (int off2 = 32; off2 > 0; off2 >>= 1) v += __shfl_down(v, off2);
        if (lane == 0) red[wave][w] = v;
    }
    __syncthreads();
    if (tid < WAY) {
        float tot = red[0][tid] + red[1][tid] + red[2][tid] + red[3][tid];
        atomicAdd(&out[(size_t)(t * WQ + q) * WAY + tid], tot);
    }
}

extern "C" void kernel_launch(void* const* d_in, const int* in_sizes, int n_in,
                              void* d_out, int out_size, void* d_ws, size_t ws_size,
                              hipStream_t stream) {
    const float* qf = (const float*)d_in[0];   // (4,75,640,10,10)
    const float* sf = (const float*)d_in[1];   // (4,25,640,10,10)
    const float* cw = (const float*)d_in[2];   // (1,1,100)
    const float* cb = (const float*)d_in[3];   // (1,)
    float* out = (float*)d_out;                // (4,75,5)

    unsigned short* covb = (unsigned short*)((char*)d_ws + WS_COVB_OFF);
    unsigned short* qtb  = (unsigned short*)((char*)d_ws + WS_QTB_OFF);
    unsigned short* qtbw = (unsigned short*)((char*)d_ws + WS_QTBW_OFF);
    unsigned short* stb  = (unsigned short*)((char*)d_ws + WS_STB_OFF);

    init_out_kernel<<<1, 256, 0, stream>>>(out, cb);
    qpack_kernel<<<dim3(10, T * WQ), 256, 0, stream>>>(qf, cw, qtb, qtbw);
    spack_kernel<<<dim3(40, T * WAY), 256, 0, stream>>>(sf, stb);
    cov_kernel<<<dim3(NPAIR, T * WAY), 256, 0, stream>>>(stb, covb);
    score_kernel<<<dim3(NPAIR, WQ, T), 256, 0, stream>>>(qtb, qtbw, covb, out);
}

// Round 12
// 240.600 us; speedup vs baseline: 1.3063x; 1.0892x over previous
//
#include <hip/hip_runtime.h>

// Problem constants
#define T     4
#define WQ    75
#define C     640
#define HW    100
#define WAY   5
#define SHOT  5
#define NT    5
#define NPAIR 15

// q tiles: [tq][tile(5)][oct(14)][row(128)][8] bf16; octet 12 half-zero, 13 zero
#define QOCT  14
#define QTS   (QOCT*128*8)        // 14336 shorts = 28 KB
// s tiles (tight k-pack): [tw][tile(5)][oct(64)][row(128)][8]; k = sh*100+n, 500 real + 12 zero
#define SOCT  64
#define STS   (SOCT*128*8)        // 65536 shorts = 128 KB

// ws layout (bytes)
#define WS_COVB_OFF  0            // 20*15*16384*2 = 9,830,400 (bf16, fragment order)
#define WS_QTB_OFF   9830400      // 300*5*14336*2 = 43,008,000
#define WS_QTBW_OFF  52838400     // 300*5*14336*2 = 43,008,000
#define WS_STB_OFF   95846400     // 20*5*65536*2  = 13,107,200

typedef __attribute__((ext_vector_type(8)))  short bfrag8;
typedef __attribute__((ext_vector_type(16))) float f32x16;

__device__ __forceinline__ unsigned short f2bf(float x) {
    unsigned int u = __float_as_uint(x);
    return (unsigned short)((u + 0x7fffu + ((u >> 16) & 1u)) >> 16);   // RNE
}
__device__ __forceinline__ float bflo(unsigned u) { return __uint_as_float(u << 16); }
__device__ __forceinline__ float bfhi(unsigned u) { return __uint_as_float(u & 0xffff0000u); }

__device__ __forceinline__ void pair_ij(int p, int& ti, int& tj) {
    int base = 0;
    #pragma unroll
    for (int a = 0; a < NT; ++a) {
        int cnt = NT - a;
        if (p < base + cnt) { ti = a; tj = a + (p - base); return; }
        base += cnt;
    }
    ti = 0; tj = 0;
}

// ---------- qpack: 32 rows/block, grid (20, 300). LDS ~14 KB; init folded in ----------
__global__ __launch_bounds__(256, 6)
void qpack_kernel(const float* __restrict__ qf, const float* __restrict__ convw,
                  const float* __restrict__ bias,
                  unsigned short* __restrict__ qtb, unsigned short* __restrict__ qtbw,
                  float* __restrict__ out) {
    __shared__ float ld[32 * 101];
    __shared__ float wl[HW];
    __shared__ float mpart[32][4];
    __shared__ float mean[32];
    int cb = blockIdx.x, tq = blockIdx.y;
    int tid = threadIdx.x;
    if (cb == 0 && tq == 0) {                    // folded out-init (runs before score)
        float b = bias[0];
        for (int i = tid; i < T * WQ * WAY; i += 256) out[i] = b;
    }
    if (tid < HW) wl[tid] = convw[tid];
    const float* src = qf + ((size_t)tq * C + cb * 32) * HW;
    #pragma unroll
    for (int it = 0; it < 4; ++it) {
        int idx = tid + it * 256;
        if (idx < 800) {                         // 32 rows x 25 float4
            float4 v = ((const float4*)src)[idx];
            int f = idx * 4;
            int row = f / HW, n = f % HW;        // float4 never crosses a row
            float* d = &ld[row * 101 + n];
            d[0] = v.x; d[1] = v.y; d[2] = v.z; d[3] = v.w;
        }
    }
    __syncthreads();
    if (tid < 128) {
        int row = tid & 31, part = tid >> 5;     // 4 parts x 25 els
        float ps = 0.f;
        #pragma unroll
        for (int i = 0; i < 25; ++i) ps += ld[row * 101 + part * 25 + i];
        mpart[row][part] = ps;
    }
    __syncthreads();
    if (tid < 32) mean[tid] = (mpart[tid][0] + mpart[tid][1] + mpart[tid][2] + mpart[tid][3]) * (1.0f / HW);
    __syncthreads();
    int crow0 = cb * 32;
    int tile = crow0 >> 7, trowbase = crow0 & 127;
    #pragma unroll
    for (int it = 0; it < 2; ++it) {
        int task = tid + it * 256;               // 448 tasks: row(32) x oct(14)
        if (task < 32 * QOCT) {
            int row = task & 31, oct = task >> 5;
            float m = mean[row];
            unsigned short ob[8] __attribute__((aligned(16)));
            unsigned short ow[8] __attribute__((aligned(16)));
            #pragma unroll
            for (int j = 0; j < 8; ++j) {
                int n = oct * 8 + j;
                float v = (n < HW) ? (ld[row * 101 + n] - m) : 0.f;
                float w = (n < HW) ? wl[n] : 0.f;
                ob[j] = f2bf(v); ow[j] = f2bf(v * w);
            }
            size_t dst = ((((size_t)tq * NT + tile) * QOCT + oct) * 128 + trowbase + row) * 8;
            *(uint4*)(qtb + dst)  = *(uint4*)ob;
            *(uint4*)(qtbw + dst) = *(uint4*)ow;
        }
    }
}

// ---------- spack: 16 rows/block, tight-k, stride 505 (conflict-free). grid (40, 20) ----------
#define LD2S 505
__global__ __launch_bounds__(256, 4)
void spack_kernel(const float* __restrict__ sf, unsigned short* __restrict__ stb) {
    __shared__ float ld2[16 * LD2S];            // [row][k], k = sh*100+n
    __shared__ float mpart2[16][16];
    __shared__ float mean2[16];
    int rb = blockIdx.x, tw = blockIdx.y;
    int tid = threadIdx.x;
    int r0 = rb * 16;
    for (int sh = 0; sh < SHOT; ++sh) {
        const float* src = sf + ((size_t)(tw * SHOT + sh) * C + r0) * HW;
        #pragma unroll
        for (int it = 0; it < 2; ++it) {
            int idx = tid + it * 256;
            if (idx < 400) {                     // 16 rows x 25 float4
                float4 v = ((const float4*)src)[idx];
                int f = idx * 4;
                int row = f / HW, n = f % HW;
                float* d = &ld2[row * LD2S + sh * HW + n];
                d[0] = v.x; d[1] = v.y; d[2] = v.z; d[3] = v.w;
            }
        }
    }
    __syncthreads();
    {
        int row = tid & 15, part = tid >> 4;    // 16 parts x 32 els
        float ps = 0.f;
        #pragma unroll
        for (int i = 0; i < 32; ++i) {
            int k = part * 32 + i;
            if (k < 500) ps += ld2[row * LD2S + k];
        }
        mpart2[row][part] = ps;
    }
    __syncthreads();
    if (tid < 16) {
        float s = 0.f;
        #pragma unroll
        for (int p2 = 0; p2 < 16; ++p2) s += mpart2[tid][p2];
        mean2[tid] = s * (1.0f / (SHOT * HW));
    }
    __syncthreads();
    #pragma unroll
    for (int it = 0; it < 4; ++it) {
        int task = tid + it * 256;              // 1024 tasks: oct(64) x row(16)
        int row = task & 15, oct = task >> 4;
        float m = mean2[row];
        unsigned short ob[8] __attribute__((aligned(16)));
        #pragma unroll
        for (int j = 0; j < 8; ++j) {
            int k = oct * 8 + j;
            ob[j] = (k < 500) ? f2bf(ld2[row * LD2S + k] - m) : (unsigned short)0;
        }
        int crow = r0 + row;
        int tile = crow >> 7, trow = crow & 127;
        size_t dst = ((((size_t)tw * NT + tile) * SOCT + oct) * 128 + trow) * 8;
        *(uint4*)(stb + dst) = *(uint4*)ob;
    }
}

// ---------- cov: direct global->VGPR fragment loads, tight k (32 s-iters) ----------
// grid = (NPAIR, T*WAY)
__global__ __launch_bounds__(256, 3)
void cov_kernel(const unsigned short* __restrict__ stb, unsigned short* __restrict__ covb) {
    int p = blockIdx.x, tw = blockIdx.y;
    int ti, tj; pair_ij(p, ti, tj);
    int tid = threadIdx.x, lane = tid & 63, wave = tid >> 6;
    int qm = wave & 1, qn = wave >> 1, lh = lane >> 5, ls = lane & 31;
    int rA = qm * 64 + ls, rB = qn * 64 + ls;
    const unsigned short* Ab = stb + ((size_t)tw * NT + ti) * STS;
    const unsigned short* Bb = stb + ((size_t)tw * NT + tj) * STS;

    f32x16 acc[4];
    #pragma unroll
    for (int b = 0; b < 4; ++b)
        #pragma unroll
        for (int e = 0; e < 16; ++e) acc[b][e] = 0.f;

    #pragma unroll 4
    for (int s = 0; s < 32; ++s) {
        int oc = s * 2 + lh;
        const unsigned short* ap = Ab + (size_t)oc * 1024;
        const unsigned short* bp = Bb + (size_t)oc * 1024;
        bfrag8 a0 = *(const bfrag8*)&ap[rA * 8];
        bfrag8 a1 = *(const bfrag8*)&ap[(rA + 32) * 8];
        bfrag8 b0 = *(const bfrag8*)&bp[rB * 8];
        bfrag8 b1 = *(const bfrag8*)&bp[(rB + 32) * 8];
        acc[0] = __builtin_amdgcn_mfma_f32_32x32x16_bf16(a0, b0, acc[0], 0, 0, 0);
        acc[1] = __builtin_amdgcn_mfma_f32_32x32x16_bf16(a0, b1, acc[1], 0, 0, 0);
        acc[2] = __builtin_amdgcn_mfma_f32_32x32x16_bf16(a1, b0, acc[2], 0, 0, 0);
        acc[3] = __builtin_amdgcn_mfma_f32_32x32x16_bf16(a1, b1, acc[3], 0, 0, 0);
    }

    const float inv = 1.0f / (HW - 1);
    unsigned short* cb = covb + ((size_t)tw * NPAIR + p) * 16384;
    #pragma unroll
    for (int b = 0; b < 4; ++b) {
        unsigned ow[8];
        #pragma unroll
        for (int wd = 0; wd < 8; ++wd)
            ow[wd] = (unsigned)f2bf(acc[b][2 * wd] * inv)
                   | ((unsigned)f2bf(acc[b][2 * wd + 1] * inv) << 16);
        size_t off = (size_t)((wave * 4 + b) * 64 + lane) * 16;
        *(uint4*)(cb + off)     = *(uint4*)&ow[0];
        *(uint4*)(cb + off + 8) = *(uint4*)&ow[4];
    }
}

// ---------- score: one query per block -> grid (p=15, q=75, t=4) = 4500 blocks ----------
__global__ __launch_bounds__(256, 3)
void score_kernel(const unsigned short* __restrict__ qtb, const unsigned short* __restrict__ qtbw,
                  const unsigned short* __restrict__ covb, float* __restrict__ out) {
    __shared__ float red[4][WAY];
    int p = blockIdx.x, q = blockIdx.y, t = blockIdx.z;
    int ti, tj; pair_ij(p, ti, tj);
    int tid = threadIdx.x, lane = tid & 63, wave = tid >> 6;
    int qm = wave & 1, qn = wave >> 1, lh = lane >> 5, ls = lane & 31;
    int rA = qm * 64 + ls, rB = qn * 64 + ls;
    float mult = (ti == tj) ? 1.0f : 2.0f;
    const unsigned short* cbase = covb + ((size_t)(t * WAY) * NPAIR + p) * 16384;

    const unsigned short* Ab = qtbw + ((size_t)(t * WQ + q) * NT + ti) * QTS;
    const unsigned short* Bb = qtb  + ((size_t)(t * WQ + q) * NT + tj) * QTS;

    f32x16 acc[4];
    #pragma unroll
    for (int b = 0; b < 4; ++b)
        #pragma unroll
        for (int e = 0; e < 16; ++e) acc[b][e] = 0.f;

    #pragma unroll
    for (int s = 0; s < 7; ++s) {
        int oc = s * 2 + lh;
        const unsigned short* ap = Ab + (size_t)oc * 1024;
        const unsigned short* bp = Bb + (size_t)oc * 1024;
        bfrag8 a0 = *(const bfrag8*)&ap[rA * 8];
        bfrag8 a1 = *(const bfrag8*)&ap[(rA + 32) * 8];
        bfrag8 b0 = *(const bfrag8*)&bp[rB * 8];
        bfrag8 b1 = *(const bfrag8*)&bp[(rB + 32) * 8];
        acc[0] = __builtin_amdgcn_mfma_f32_32x32x16_bf16(a0, b0, acc[0], 0, 0, 0);
        acc[1] = __builtin_amdgcn_mfma_f32_32x32x16_bf16(a0, b1, acc[1], 0, 0, 0);
        acc[2] = __builtin_amdgcn_mfma_f32_32x32x16_bf16(a1, b0, acc[2], 0, 0, 0);
        acc[3] = __builtin_amdgcn_mfma_f32_32x32x16_bf16(a1, b1, acc[3], 0, 0, 0);
    }

    // per-way Frobenius dot + immediate reduce
    #pragma unroll 1
    for (int w = 0; w < WAY; ++w) {
        const unsigned short* cb = cbase + (size_t)w * NPAIR * 16384;
        float s = 0.f;
        #pragma unroll
        for (int b = 0; b < 4; ++b) {
            size_t off = (size_t)((wave * 4 + b) * 64 + lane) * 16;
            uint4 u0 = *(const uint4*)(cb + off);
            uint4 u1 = *(const uint4*)(cb + off + 8);
            unsigned uw[8] = {u0.x, u0.y, u0.z, u0.w, u1.x, u1.y, u1.z, u1.w};
            #pragma unroll
            for (int wd = 0; wd < 8; ++wd)
                s += bflo(uw[wd]) * acc[b][2 * wd] + bfhi(uw[wd]) * acc[b][2 * wd + 1];
        }
        float v = s * mult;
        #pragma unroll
        for (int off2 = 32; off2 > 0; off2 >>= 1) v += __shfl_down(v, off2);
        if (lane == 0) red[wave][w] = v;
    }
    __syncthreads();
    if (tid < WAY) {
        float tot = red[0][tid] + red[1][tid] + red[2][tid] + red[3][tid];
        atomicAdd(&out[(size_t)(t * WQ + q) * WAY + tid], tot);
    }
}

extern "C" void kernel_launch(void* const* d_in, const int* in_sizes, int n_in,
                              void* d_out, int out_size, void* d_ws, size_t ws_size,
                              hipStream_t stream) {
    const float* qf = (const float*)d_in[0];   // (4,75,640,10,10)
    const float* sf = (const float*)d_in[1];   // (4,25,640,10,10)
    const float* cw = (const float*)d_in[2];   // (1,1,100)
    const float* cb = (const float*)d_in[3];   // (1,)
    float* out = (float*)d_out;                // (4,75,5)

    unsigned short* covb = (unsigned short*)((char*)d_ws + WS_COVB_OFF);
    unsigned short* qtb  = (unsigned short*)((char*)d_ws + WS_QTB_OFF);
    unsigned short* qtbw = (unsigned short*)((char*)d_ws + WS_QTBW_OFF);
    unsigned short* stb  = (unsigned short*)((char*)d_ws + WS_STB_OFF);

    qpack_kernel<<<dim3(20, T * WQ), 256, 0, stream>>>(qf, cw, cb, qtb, qtbw, out);
    spack_kernel<<<dim3(40, T * WAY), 256, 0, stream>>>(sf, stb);
    cov_kernel<<<dim3(NPAIR, T * WAY), 256, 0, stream>>>(stb, covb);
    score_kernel<<<dim3(NPAIR, WQ, T), 256, 0, stream>>>(qtb, qtbw, covb, out);
}

// Round 13
// 228.998 us; speedup vs baseline: 1.3725x; 1.0507x over previous
//
#include <hip/hip_runtime.h>

// Problem constants
#define T     4
#define WQ    75
#define C     640
#define HW    100
#define WAY   5
#define SHOT  5
#define NT    5
#define NPAIR 15

// q tiles: [tq][tile(5)][oct(14)][row(128)][8] bf16; octet 12 half-zero, 13 zero
#define QOCT  14
#define QTS   (QOCT*128*8)        // 14336 shorts = 28 KB
// s tiles (tight k-pack): [tw][tile(5)][oct(64)][row(128)][8]; k = sh*100+n, 500 real + 12 zero
#define SOCT  64
#define STS   (SOCT*128*8)        // 65536 shorts = 128 KB

// ws layout (bytes)
#define WS_COVB_OFF  0            // 20*15*16384*2 = 9,830,400 (bf16, fragment order)
#define WS_QTB_OFF   9830400      // 300*5*14336*2 = 43,008,000
#define WS_QTBW_OFF  52838400     // 300*5*14336*2 = 43,008,000
#define WS_STB_OFF   95846400     // 20*5*65536*2  = 13,107,200

typedef __attribute__((ext_vector_type(8)))  short bfrag8;
typedef __attribute__((ext_vector_type(16))) float f32x16;

__device__ __forceinline__ unsigned short f2bf(float x) {
    unsigned int u = __float_as_uint(x);
    return (unsigned short)((u + 0x7fffu + ((u >> 16) & 1u)) >> 16);   // RNE
}
__device__ __forceinline__ float bflo(unsigned u) { return __uint_as_float(u << 16); }
__device__ __forceinline__ float bfhi(unsigned u) { return __uint_as_float(u & 0xffff0000u); }

__device__ __forceinline__ void pair_ij(int p, int& ti, int& tj) {
    int base = 0;
    #pragma unroll
    for (int a = 0; a < NT; ++a) {
        int cnt = NT - a;
        if (p < base + cnt) { ti = a; tj = a + (p - base); return; }
        base += cnt;
    }
    ti = 0; tj = 0;
}

// ---------- spack: 16 rows/block, tight-k, stride 505 (conflict-free). grid (40, 20) ----------
#define LD2S 505
__global__ __launch_bounds__(256, 4)
void spack_kernel(const float* __restrict__ sf, unsigned short* __restrict__ stb) {
    __shared__ float ld2[16 * LD2S];            // [row][k], k = sh*100+n
    __shared__ float mpart2[16][16];
    __shared__ float mean2[16];
    int rb = blockIdx.x, tw = blockIdx.y;
    int tid = threadIdx.x;
    int r0 = rb * 16;
    for (int sh = 0; sh < SHOT; ++sh) {
        const float* src = sf + ((size_t)(tw * SHOT + sh) * C + r0) * HW;
        #pragma unroll
        for (int it = 0; it < 2; ++it) {
            int idx = tid + it * 256;
            if (idx < 400) {                     // 16 rows x 25 float4
                float4 v = ((const float4*)src)[idx];
                int f = idx * 4;
                int row = f / HW, n = f % HW;    // float4 never crosses a row
                float* d = &ld2[row * LD2S + sh * HW + n];
                d[0] = v.x; d[1] = v.y; d[2] = v.z; d[3] = v.w;
            }
        }
    }
    __syncthreads();
    {
        int row = tid & 15, part = tid >> 4;    // 16 parts x 32 els
        float ps = 0.f;
        #pragma unroll
        for (int i = 0; i < 32; ++i) {
            int k = part * 32 + i;
            if (k < 500) ps += ld2[row * LD2S + k];
        }
        mpart2[row][part] = ps;
    }
    __syncthreads();
    if (tid < 16) {
        float s = 0.f;
        #pragma unroll
        for (int p2 = 0; p2 < 16; ++p2) s += mpart2[tid][p2];
        mean2[tid] = s * (1.0f / (SHOT * HW));
    }
    __syncthreads();
    #pragma unroll
    for (int it = 0; it < 4; ++it) {
        int task = tid + it * 256;              // 1024 tasks: oct(64) x row(16)
        int row = task & 15, oct = task >> 4;
        float m = mean2[row];
        unsigned short ob[8] __attribute__((aligned(16)));
        #pragma unroll
        for (int j = 0; j < 8; ++j) {
            int k = oct * 8 + j;
            ob[j] = (k < 500) ? f2bf(ld2[row * LD2S + k] - m) : (unsigned short)0;
        }
        int crow = r0 + row;
        int tile = crow >> 7, trow = crow & 127;
        size_t dst = ((((size_t)tw * NT + tile) * SOCT + oct) * 128 + trow) * 8;
        *(uint4*)(stb + dst) = *(uint4*)ob;
    }
}

// ---------- merged cov + qpack: blocks 0..299 cov (runs first, overlaps qpack) ----------
// blocks 300..6299 qpack (cb = idx%20, tq = idx/20); out-init folded into qpack idx 0.
__global__ __launch_bounds__(256, 3)
void packcov_kernel(const float* __restrict__ qf, const float* __restrict__ convw,
                    const float* __restrict__ bias, const unsigned short* __restrict__ stb,
                    unsigned short* __restrict__ qtb, unsigned short* __restrict__ qtbw,
                    unsigned short* __restrict__ covb, float* __restrict__ out) {
    int bid = blockIdx.x, tid = threadIdx.x;

    if (bid < 300) {
        // ---- cov: direct global->VGPR fragment loads, tight k (32 s-iters) ----
        int p = bid % NPAIR, tw = bid / NPAIR;
        int ti, tj; pair_ij(p, ti, tj);
        int lane = tid & 63, wave = tid >> 6;
        int qm = wave & 1, qn = wave >> 1, lh = lane >> 5, ls = lane & 31;
        int rA = qm * 64 + ls, rB = qn * 64 + ls;
        const unsigned short* Ab = stb + ((size_t)tw * NT + ti) * STS;
        const unsigned short* Bb = stb + ((size_t)tw * NT + tj) * STS;

        f32x16 acc[4];
        #pragma unroll
        for (int b = 0; b < 4; ++b)
            #pragma unroll
            for (int e = 0; e < 16; ++e) acc[b][e] = 0.f;

        #pragma unroll 4
        for (int s = 0; s < 32; ++s) {
            int oc = s * 2 + lh;
            const unsigned short* ap = Ab + (size_t)oc * 1024;
            const unsigned short* bp = Bb + (size_t)oc * 1024;
            bfrag8 a0 = *(const bfrag8*)&ap[rA * 8];
            bfrag8 a1 = *(const bfrag8*)&ap[(rA + 32) * 8];
            bfrag8 b0 = *(const bfrag8*)&bp[rB * 8];
            bfrag8 b1 = *(const bfrag8*)&bp[(rB + 32) * 8];
            acc[0] = __builtin_amdgcn_mfma_f32_32x32x16_bf16(a0, b0, acc[0], 0, 0, 0);
            acc[1] = __builtin_amdgcn_mfma_f32_32x32x16_bf16(a0, b1, acc[1], 0, 0, 0);
            acc[2] = __builtin_amdgcn_mfma_f32_32x32x16_bf16(a1, b0, acc[2], 0, 0, 0);
            acc[3] = __builtin_amdgcn_mfma_f32_32x32x16_bf16(a1, b1, acc[3], 0, 0, 0);
        }

        const float inv = 1.0f / (HW - 1);
        unsigned short* cb = covb + ((size_t)tw * NPAIR + p) * 16384;
        #pragma unroll
        for (int b = 0; b < 4; ++b) {
            unsigned ow[8];
            #pragma unroll
            for (int wd = 0; wd < 8; ++wd)
                ow[wd] = (unsigned)f2bf(acc[b][2 * wd] * inv)
                       | ((unsigned)f2bf(acc[b][2 * wd + 1] * inv) << 16);
            size_t off = (size_t)((wave * 4 + b) * 64 + lane) * 16;
            *(uint4*)(cb + off)     = *(uint4*)&ow[0];
            *(uint4*)(cb + off + 8) = *(uint4*)&ow[4];
        }
    } else {
        // ---- qpack: 32 rows/block ----
        __shared__ float ld[32 * 101];
        __shared__ float wl[HW];
        __shared__ float mpart[32][4];
        __shared__ float mean[32];
        int idx0 = bid - 300;
        int cb = idx0 % 20, tq = idx0 / 20;
        if (idx0 == 0) {                         // folded out-init (completes before score)
            float b = bias[0];
            for (int i = tid; i < T * WQ * WAY; i += 256) out[i] = b;
        }
        if (tid < HW) wl[tid] = convw[tid];
        const float* src = qf + ((size_t)tq * C + cb * 32) * HW;
        #pragma unroll
        for (int it = 0; it < 4; ++it) {
            int idx = tid + it * 256;
            if (idx < 800) {                     // 32 rows x 25 float4
                float4 v = ((const float4*)src)[idx];
                int f = idx * 4;
                int row = f / HW, n = f % HW;
                float* d = &ld[row * 101 + n];
                d[0] = v.x; d[1] = v.y; d[2] = v.z; d[3] = v.w;
            }
        }
        __syncthreads();
        if (tid < 128) {
            int row = tid & 31, part = tid >> 5;
            float ps = 0.f;
            #pragma unroll
            for (int i = 0; i < 25; ++i) ps += ld[row * 101 + part * 25 + i];
            mpart[row][part] = ps;
        }
        __syncthreads();
        if (tid < 32) mean[tid] = (mpart[tid][0] + mpart[tid][1] + mpart[tid][2] + mpart[tid][3]) * (1.0f / HW);
        __syncthreads();
        int crow0 = cb * 32;
        int tile = crow0 >> 7, trowbase = crow0 & 127;
        #pragma unroll
        for (int it = 0; it < 2; ++it) {
            int task = tid + it * 256;           // 448 tasks: row(32) x oct(14)
            if (task < 32 * QOCT) {
                int row = task & 31, oct = task >> 5;
                float m = mean[row];
                unsigned short ob[8] __attribute__((aligned(16)));
                unsigned short ow[8] __attribute__((aligned(16)));
                #pragma unroll
                for (int j = 0; j < 8; ++j) {
                    int n = oct * 8 + j;
                    float v = (n < HW) ? (ld[row * 101 + n] - m) : 0.f;
                    float w = (n < HW) ? wl[n] : 0.f;
                    ob[j] = f2bf(v); ow[j] = f2bf(v * w);
                }
                size_t dst = ((((size_t)tq * NT + tile) * QOCT + oct) * 128 + trowbase + row) * 8;
                *(uint4*)(qtb + dst)  = *(uint4*)ob;
                *(uint4*)(qtbw + dst) = *(uint4*)ow;
            }
        }
    }
}

// ---------- score: grid (q=75, p=15, t=4); consecutive blocks share (t,p) cov in L2 ----------
__global__ __launch_bounds__(256, 3)
void score_kernel(const unsigned short* __restrict__ qtb, const unsigned short* __restrict__ qtbw,
                  const unsigned short* __restrict__ covb, float* __restrict__ out) {
    __shared__ float red[4][WAY];
    int q = blockIdx.x, p = blockIdx.y, t = blockIdx.z;
    int ti, tj; pair_ij(p, ti, tj);
    int tid = threadIdx.x, lane = tid & 63, wave = tid >> 6;
    int qm = wave & 1, qn = wave >> 1, lh = lane >> 5, ls = lane & 31;
    int rA = qm * 64 + ls, rB = qn * 64 + ls;
    float mult = (ti == tj) ? 1.0f : 2.0f;
    const unsigned short* cbase = covb + ((size_t)(t * WAY) * NPAIR + p) * 16384;

    const unsigned short* Ab = qtbw + ((size_t)(t * WQ + q) * NT + ti) * QTS;
    const unsigned short* Bb = qtb  + ((size_t)(t * WQ + q) * NT + tj) * QTS;

    f32x16 acc[4];
    #pragma unroll
    for (int b = 0; b < 4; ++b)
        #pragma unroll
        for (int e = 0; e < 16; ++e) acc[b][e] = 0.f;

    #pragma unroll
    for (int s = 0; s < 7; ++s) {
        int oc = s * 2 + lh;
        const unsigned short* ap = Ab + (size_t)oc * 1024;
        const unsigned short* bp = Bb + (size_t)oc * 1024;
        bfrag8 a0 = *(const bfrag8*)&ap[rA * 8];
        bfrag8 a1 = *(const bfrag8*)&ap[(rA + 32) * 8];
        bfrag8 b0 = *(const bfrag8*)&bp[rB * 8];
        bfrag8 b1 = *(const bfrag8*)&bp[(rB + 32) * 8];
        acc[0] = __builtin_amdgcn_mfma_f32_32x32x16_bf16(a0, b0, acc[0], 0, 0, 0);
        acc[1] = __builtin_amdgcn_mfma_f32_32x32x16_bf16(a0, b1, acc[1], 0, 0, 0);
        acc[2] = __builtin_amdgcn_mfma_f32_32x32x16_bf16(a1, b0, acc[2], 0, 0, 0);
        acc[3] = __builtin_amdgcn_mfma_f32_32x32x16_bf16(a1, b1, acc[3], 0, 0, 0);
    }

    // per-way Frobenius dot + immediate reduce
    #pragma unroll 1
    for (int w = 0; w < WAY; ++w) {
        const unsigned short* cb = cbase + (size_t)w * NPAIR * 16384;
        float s = 0.f;
        #pragma unroll
        for (int b = 0; b < 4; ++b) {
            size_t off = (size_t)((wave * 4 + b) * 64 + lane) * 16;
            uint4 u0 = *(const uint4*)(cb + off);
            uint4 u1 = *(const uint4*)(cb + off + 8);
            unsigned uw[8] = {u0.x, u0.y, u0.z, u0.w, u1.x, u1.y, u1.z, u1.w};
            #pragma unroll
            for (int wd = 0; wd < 8; ++wd)
                s += bflo(uw[wd]) * acc[b][2 * wd] + bfhi(uw[wd]) * acc[b][2 * wd + 1];
        }
        float v = s * mult;
        #pragma unroll
        for (int off2 = 32; off2 > 0; off2 >>= 1) v += __shfl_down(v, off2);
        if (lane == 0) red[wave][w] = v;
    }
    __syncthreads();
    if (tid < WAY) {
        float tot = red[0][tid] + red[1][tid] + red[2][tid] + red[3][tid];
        atomicAdd(&out[(size_t)(t * WQ + q) * WAY + tid], tot);
    }
}

extern "C" void kernel_launch(void* const* d_in, const int* in_sizes, int n_in,
                              void* d_out, int out_size, void* d_ws, size_t ws_size,
                              hipStream_t stream) {
    const float* qf = (const float*)d_in[0];   // (4,75,640,10,10)
    const float* sf = (const float*)d_in[1];   // (4,25,640,10,10)
    const float* cw = (const float*)d_in[2];   // (1,1,100)
    const float* cb = (const float*)d_in[3];   // (1,)
    float* out = (float*)d_out;                // (4,75,5)

    unsigned short* covb = (unsigned short*)((char*)d_ws + WS_COVB_OFF);
    unsigned short* qtb  = (unsigned short*)((char*)d_ws + WS_QTB_OFF);
    unsigned short* qtbw = (unsigned short*)((char*)d_ws + WS_QTBW_OFF);
    unsigned short* stb  = (unsigned short*)((char*)d_ws + WS_STB_OFF);

    spack_kernel<<<dim3(40, T * WAY), 256, 0, stream>>>(sf, stb);
    packcov_kernel<<<6300, 256, 0, stream>>>(qf, cw, cb, stb, qtb, qtbw, covb, out);
    score_kernel<<<dim3(WQ, NPAIR, T), 256, 0, stream>>>(qtb, qtbw, covb, out);
}